// Round 13
// baseline (170.767 us; speedup 1.0000x reference)
//
#include <hip/hip_runtime.h>

// Problem constants (fixed by the reference)
#define NNZ_    524288               // = 2^19: triple idx fits 19 bits
#define OUT_    8192
#define TPB     256
#define NBLK1   1024                 // K1 blocks -> 512 triples each, 4 blocks/CU
#define TPBLK   (NNZ_ / NBLK1)       // 512
#define ITER1   (TPBLK / TPB)        // 2
#define TBLOG   22
#define TBSLOTS (1u << TBLOG)        // dedupe table: 4M x 4B = 16 MiB (hashed keys)
#define HLOG    17
#define HSLOTS  (1u << HLOG)         // fix hash: 2^17 x 8B = 1 MiB
#define HMASK   (HSLOTS - 1u)
#define POISON  0xAAAAAAAAAAAAAAAAull  // ws re-poisoned to 0xAA each call = empty sentinel

__device__ __forceinline__ unsigned tbl_h(unsigned key) {
    return (key * 2654435761u) >> (32 - TBLOG);   // Fibonacci, top 22 bits
}

// K1: NO device atomics. Each block accumulates ALL its triples' contributions
// into a private LDS copy of the full output vector (32 KB), then streams it
// out as a partial. Dedupe DETECTION is a plain fire-and-forget store of the
// triple index into a hashed table — the race winner is arbitrary; K3 is
// robust to any outcome (including cross-XCD writeback clobber: a slot not
// holding a same-key index just routes the whole group to self-insert).
__global__ void __launch_bounds__(TPB) accum_kernel(
    const int* __restrict__ rows, const int* __restrict__ cols,
    const int* __restrict__ wpos, const float* __restrict__ W,
    const float* __restrict__ x,
    int* __restrict__ tbl, float* __restrict__ part)
{
    __shared__ float acc[OUT_];                  // 32 KB: the whole output
    for (int s = threadIdx.x; s < OUT_; s += TPB) acc[s] = 0.f;
    __syncthreads();
    const int base = blockIdx.x * TPBLK;
#pragma unroll
    for (int it = 0; it < ITER1; ++it) {
        const int idx = base + it * TPB + threadIdx.x;   // coalesced streams
        const int r = rows[idx], c = cols[idx], w = wpos[idx];
        atomicAdd(&acc[c], x[r] * W[w]);         // LDS atomic: on-CU, no fabric
        const unsigned key = ((unsigned)r << 13) | (unsigned)c;
        tbl[tbl_h(key)] = idx;                   // plain store, fire-and-forget
    }
    __syncthreads();
    float4* p4 = (float4*)(part + (size_t)blockIdx.x * OUT_);
    const float4* a4 = (const float4*)acc;
    for (int s = threadIdx.x; s < OUT_ / 4; s += TPB) p4[s] = a4[s];  // 32 KB stream
}

// K2: out[c] = sum over 1024 partials + bias. Pure coalesced loads, no atomics.
__global__ void __launch_bounds__(TPB) reduce_kernel(
    const float* __restrict__ part, const float* __restrict__ b,
    const int* __restrict__ bias_pos, float* __restrict__ out)
{
    const int c = blockIdx.x * TPB + threadIdx.x;        // grid = 32 blocks
    float s0 = 0.f, s1 = 0.f, s2 = 0.f, s3 = 0.f;
    for (int blk = 0; blk < NBLK1; blk += 4) {           // 4-way ILP
        s0 += part[(size_t)(blk + 0) * OUT_ + c];
        s1 += part[(size_t)(blk + 1) * OUT_ + c];
        s2 += part[(size_t)(blk + 2) * OUT_ + c];
        s3 += part[(size_t)(blk + 3) * OUT_ + c];
    }
    out[c] = (s0 + s1) + (s2 + s3) + b[bias_pos[c]];
}

// Fix-hash insert with telescoping subtraction (protocol proven r11/r12,
// absmax 0.0). Inserting a key's members exactly once each subtracts every
// non-max member exactly once. Returns true iff this call claimed the slot.
// old==packed guard makes accidental duplicate inserts no-ops.
__device__ bool fix_insert(unsigned key, int v, int c, float xr,
                           const int* __restrict__ wpos,
                           const float* __restrict__ W,
                           unsigned long long* __restrict__ fixh,
                           float* __restrict__ out)
{
    const unsigned long long kh = (unsigned long long)(key + 1u);  // <= 2^26
    const unsigned long long packed = (kh << 19) | (unsigned)v;    // < 2^46 != POISON
    unsigned s = (key * 2654435761u) >> (32 - HLOG);
    while (true) {
        s &= HMASK;
        unsigned long long cur = fixh[s];
        while (cur == POISON) {                  // claim empty (poison) slot
            unsigned long long prev = atomicCAS(&fixh[s], cur, packed);
            if (prev == cur) return true;        // claimed; no subtraction
            cur = prev;
        }
        if ((cur >> 19) == kh) {                 // my key's resident slot
            const unsigned long long old = atomicMax(&fixh[s], packed);
            if (old != packed) {                 // (==: duplicate insert, no-op)
                if (old < packed) {              // displaced old -> subtract old
                    const int oi = (int)(old & 0x7FFFFull);
                    atomicAdd(&out[c], -xr * W[wpos[oi]]);  // same key => same r,c
                } else {                         // rejected -> subtract myself
                    atomicAdd(&out[c], -xr * W[wpos[v]]);
                }
            }
            return false;
        }
        ++s;                                     // foreign key: linear probe
    }
}

// K3: exact numpy last-write-wins repair. Baseline (K1+K2) summed ALL
// contributions; for each duplicate (row,col) group, subtract every non-max
// member exactly once. Membership discovery: j = tbl[h(key)].
//   j == i                : race winner / clean singleton -> nothing.
//   j same key            : dup sibling -> self-insert; the unique claimer
//                           also inserts j (so j is inserted exactly once).
//   j foreign/garbage     : slot stolen or clobbered -> every member of my
//                           group (incl. its race winner) sees this -> all
//                           self-insert; singleton claims harmlessly.
// Device atomics here: only ~4-40k total (dups + hash-collision extras).
__global__ void __launch_bounds__(TPB) fix_kernel(
    const int* __restrict__ rows, const int* __restrict__ cols,
    const int* __restrict__ wpos, const float* __restrict__ W,
    const float* __restrict__ x, const int* __restrict__ tbl,
    unsigned long long* __restrict__ fixh, float* __restrict__ out)
{
    const int i = blockIdx.x * TPB + threadIdx.x;        // grid = 2048
    const int r = rows[i], c = cols[i];
    const unsigned key = ((unsigned)r << 13) | (unsigned)c;
    const int j = tbl[tbl_h(key)];                       // random 4B load (IC-hot)
    if (j == i) return;                                  // the common case
    bool samekey = false;
    if (j >= 0 && j < NNZ_)
        samekey = ((((unsigned)rows[j] << 13) | (unsigned)cols[j]) == key);
    const float xr = x[r];
    const bool claimed = fix_insert(key, i, c, xr, wpos, W, fixh, out);
    if (claimed && samekey)
        fix_insert(key, j, c, xr, wpos, W, fixh, out);
}

extern "C" void kernel_launch(void* const* d_in, const int* in_sizes, int n_in,
                              void* d_out, int out_size, void* d_ws, size_t ws_size,
                              hipStream_t stream) {
    const float* x    = (const float*)d_in[0];
    const float* Pw   = (const float*)d_in[1];
    const float* Pb   = (const float*)d_in[2];
    const int*   rows = (const int*)d_in[3];
    const int*   cols = (const int*)d_in[4];
    const int*   wpos = (const int*)d_in[5];
    const int*   bpos = (const int*)d_in[6];
    float*       out  = (float*)d_out;

    // ws: tbl 16 MiB | part 32 MiB | fixh 1 MiB  (<< 256 MiB; NO memset anywhere)
    int*   tbl  = (int*)d_ws;
    float* part = (float*)((char*)d_ws + (16u << 20));
    unsigned long long* fixh =
        (unsigned long long*)((char*)d_ws + (48u << 20));

    accum_kernel <<<NBLK1,      TPB, 0, stream>>>(rows, cols, wpos, Pw, x, tbl, part);
    reduce_kernel<<<OUT_ / TPB, TPB, 0, stream>>>(part, Pb, bpos, out);
    fix_kernel   <<<NNZ_ / TPB, TPB, 0, stream>>>(rows, cols, wpos, Pw, x, tbl, fixh, out);
}